// Round 11
// baseline (234.638 us; speedup 1.0000x reference)
//
#include <hip/hip_runtime.h>

#define B_ 2
#define N_ 4096
#define M_ 2048
#define D_ 256
#define H_ 8
#define DH_ 32
#define ROWS_ (B_*N_)
#define KVROWS_ (B_*M_)
// SCALE * log2(e): q pre-scaled so softmax = exp2
#define PRE_ (0.17677669529663687f * 1.4426950408889634f)
#define CBASE_ 32.0f

typedef __attribute__((ext_vector_type(8))) short short8_t;
typedef __attribute__((ext_vector_type(4))) float float4_t;

__device__ __forceinline__ unsigned short f2us(float f) {
    union { float f; unsigned int u; } c;
    c.f = f;
    unsigned int u = c.u;
    unsigned int r = u + 0x7FFFu + ((u >> 16) & 1u);  // RTNE
    return (unsigned short)(r >> 16);
}

__device__ __forceinline__ unsigned int pack2rn(float a, float b) {
    return (unsigned int)f2us(a) | ((unsigned int)f2us(b) << 16);
}

// truncation pack (P tiles only; <=2^-8 rel err)
__device__ __forceinline__ unsigned int pack2tr(float a, float b) {
    union { float f; unsigned int u; } x, y;
    x.f = a; y.f = b;
    return (x.u >> 16) | (y.u & 0xFFFF0000u);
}

__device__ __forceinline__ short8_t cvt8(float4 a, float4 b) {
    union { unsigned int u[4]; short8_t s; } c;
    c.u[0] = pack2rn(a.x, a.y);
    c.u[1] = pack2rn(a.z, a.w);
    c.u[2] = pack2rn(b.x, b.y);
    c.u[3] = pack2rn(b.z, b.w);
    return c.s;
}

// ---------------------------------------------------------------------------
// pf[row,o] = points[row,:] @ Wp[o,:] + bp[o]
// ---------------------------------------------------------------------------
__global__ __launch_bounds__(256) void n_pf(
    const float* __restrict__ points, const float* __restrict__ Wp,
    const float* __restrict__ bp, unsigned short* __restrict__ pf_g)
{
    const int row = blockIdx.x;
    const int o = threadIdx.x;
    const float p0 = points[(size_t)row * 3 + 0];
    const float p1 = points[(size_t)row * 3 + 1];
    const float p2 = points[(size_t)row * 3 + 2];
    float v = p0 * Wp[o * 3 + 0] + p1 * Wp[o * 3 + 1] + p2 * Wp[o * 3 + 2] + bp[o];
    pf_g[(size_t)row * D_ + o] = f2us(v);
}

// ---------------------------------------------------------------------------
// Stage NCOL x K fp32 weight block into XOR-swizzled bf16 LDS.
// chunk c of row n stored at chunk c ^ (n & 7).
// ---------------------------------------------------------------------------
template<int K, int NCOL>
__device__ __forceinline__ void stageB(const float* __restrict__ W, int col0,
                                       unsigned short* __restrict__ Bs, int tid)
{
    const int n = tid & (NCOL - 1), g = tid / NCOL;
    const int GROUPS = 256 / NCOL;
    const int CPT = (K / 8) / GROUPS;
    const float* src = W + (size_t)(col0 + n) * K + g * (K / GROUPS);
#pragma unroll
    for (int ci = 0; ci < CPT; ci++) {
        int logc = g * CPT + ci;
        int phys = logc ^ (n & 7);
        short8_t v = cvt8(*(const float4*)(src + ci * 8), *(const float4*)(src + ci * 8 + 4));
        *(short8_t*)(Bs + (size_t)n * K + phys * 8) = v;
    }
}

template<int K>
__device__ __forceinline__ short8_t readB(const unsigned short* __restrict__ Bs,
                                          int c, int l16, int quad, int k0)
{
    int phys = ((k0 >> 3) + quad) ^ (l16 & 7);
    return *(const short8_t*)(Bs + (size_t)(16 * c + l16) * K + phys * 8);
}

// ---------------------------------------------------------------------------
// Merged projection kernel. blocks [0,512): q = pf@Wq.T+bq (PRE_-scaled).
// blocks [512,768): k = voxel@Wk.T+bk, v = voxel@Wv.T+bv (v transposed),
// two passes over a single 32KB B-stage so both roles have equal LDS.
// ---------------------------------------------------------------------------
__global__ __launch_bounds__(256) void g_qkv(
    const unsigned short* __restrict__ pf_g, const float* __restrict__ voxel,
    const float* __restrict__ Wq, const float* __restrict__ bq,
    const float* __restrict__ Wk, const float* __restrict__ bk,
    const float* __restrict__ Wv, const float* __restrict__ bv,
    unsigned short* __restrict__ q_g, unsigned short* __restrict__ k_g,
    unsigned short* __restrict__ vt_g)
{
    const int tid = threadIdx.x;
    const int wave = tid >> 6, lane = tid & 63, quad = lane >> 4, l16 = lane & 15;

    __shared__ unsigned short Bs[64 * 256];  // 32 KB

    if (blockIdx.x < 512) {
        const int row0 = ((int)blockIdx.x >> 2) * 64;
        const int col0 = ((int)blockIdx.x & 3) * 64;
        stageB<256, 64>(Wq, col0, Bs, tid);
        __syncthreads();
        float4_t acc[4];
#pragma unroll
        for (int c = 0; c < 4; c++) acc[c] = (float4_t){0.f, 0.f, 0.f, 0.f};
        const unsigned short* arow = pf_g + (size_t)(row0 + wave * 16 + l16) * D_;
#pragma unroll
        for (int k0 = 0; k0 < 256; k0 += 32) {
            short8_t af = *(const short8_t*)(arow + k0 + quad * 8);
#pragma unroll
            for (int c = 0; c < 4; c++)
                acc[c] = __builtin_amdgcn_mfma_f32_16x16x32_bf16(af, readB<256>(Bs, c, l16, quad, k0), acc[c], 0, 0, 0);
        }
#pragma unroll
        for (int c = 0; c < 4; c++) {
            int col = col0 + 16 * c + l16;
            float bb = bq[col];
#pragma unroll
            for (int r = 0; r < 4; r++) {
                int row = row0 + wave * 16 + quad * 4 + r;
                q_g[(size_t)row * D_ + col] = f2us((acc[c][r] + bb) * PRE_);
            }
        }
    } else {
        const int bid = (int)blockIdx.x - 512;
        const int row0 = (bid >> 2) * 64;
        const int col0 = (bid & 3) * 64;
        const float* arow = voxel + (size_t)(row0 + wave * 16 + l16) * D_;

        float4_t ak[4], av[4];
#pragma unroll
        for (int c = 0; c < 4; c++) {
            ak[c] = (float4_t){0.f, 0.f, 0.f, 0.f};
            av[c] = (float4_t){0.f, 0.f, 0.f, 0.f};
        }
        // pass 1: K
        stageB<256, 64>(Wk, col0, Bs, tid);
        __syncthreads();
#pragma unroll
        for (int k0 = 0; k0 < 256; k0 += 32) {
            short8_t af = cvt8(*(const float4*)(arow + k0 + quad * 8),
                               *(const float4*)(arow + k0 + quad * 8 + 4));
#pragma unroll
            for (int c = 0; c < 4; c++)
                ak[c] = __builtin_amdgcn_mfma_f32_16x16x32_bf16(af, readB<256>(Bs, c, l16, quad, k0), ak[c], 0, 0, 0);
        }
        __syncthreads();
        // pass 2: V
        stageB<256, 64>(Wv, col0, Bs, tid);
        __syncthreads();
#pragma unroll
        for (int k0 = 0; k0 < 256; k0 += 32) {
            short8_t af = cvt8(*(const float4*)(arow + k0 + quad * 8),
                               *(const float4*)(arow + k0 + quad * 8 + 4));
#pragma unroll
            for (int c = 0; c < 4; c++)
                av[c] = __builtin_amdgcn_mfma_f32_16x16x32_bf16(af, readB<256>(Bs, c, l16, quad, k0), av[c], 0, 0, 0);
        }
        const int b = row0 / M_;
        const int m0 = row0 - b * M_ + wave * 16 + quad * 4;
#pragma unroll
        for (int c = 0; c < 4; c++) {
            int col = col0 + 16 * c + l16;
            float bbk = bk[col], bbv = bv[col];
#pragma unroll
            for (int r = 0; r < 4; r++) {
                int row = row0 + wave * 16 + quad * 4 + r;
                k_g[(size_t)row * D_ + col] = f2us(ak[c][r] + bbk);
            }
            int h = col >> 5, dh = col & 31;
            unsigned int u0 = pack2rn(av[c][0] + bbv, av[c][1] + bbv);
            unsigned int u1 = pack2rn(av[c][2] + bbv, av[c][3] + bbv);
            *(uint2*)(vt_g + (size_t)((b * H_ + h) * DH_ + dh) * M_ + m0) = make_uint2(u0, u1);
        }
    }
}

// ---------------------------------------------------------------------------
// MFMA flash attention, static-base softmax, kv-split x2 within the block.
// 512 threads = 8 waves: wave w handles q-tile (w&3), kv half (w>>2).
// Partials combine ADDITIVELY (no max state) via LDS at block end.
// exp2f (NOT inline asm): compiler-known op so TRANS-use hazard nops are
// inserted — raw asm v_exp_f32 gave stale-register reads (round 10, absmax 127).
// ---------------------------------------------------------------------------
__global__ __launch_bounds__(512) void k_attn4(
    const unsigned short* __restrict__ q_g,
    const unsigned short* __restrict__ k_g,
    const unsigned short* __restrict__ vt_g,
    unsigned short* __restrict__ att_g)
{
    const int tid = threadIdx.x;
    const int w = tid >> 6, lane = tid & 63, quad = lane >> 4, l16 = lane & 15;
    const int qw = w & 3, half = w >> 2;
    const int nt = blockIdx.x & 63;
    const int bh = blockIdx.x >> 6;
    const int b = bh >> 3, h = bh & 7;
    const int n0 = nt * 64 + qw * 16;

    __shared__ unsigned short Pb[8][2][16 * 64];  // 32 KB

    short8_t qf = *(const short8_t*)(q_g + (size_t)(b * N_ + n0 + l16) * D_ + h * DH_ + quad * 8);

    float4_t od0 = {0.f, 0.f, 0.f, 0.f};
    float4_t od1 = {0.f, 0.f, 0.f, 0.f};
    float l_lane = 0.f;

    const unsigned short* kbase = k_g + (size_t)(b * M_) * D_ + h * DH_;
    const unsigned short* vbase = vt_g + (size_t)(bh * DH_) * M_;
    const int h7 = l16 & 7;
    const int kvbeg = half * (M_ / 2), kvend = kvbeg + (M_ / 2);
    const float4_t zc = {-CBASE_, -CBASE_, -CBASE_, -CBASE_};

    for (int kv0 = kvbeg; kv0 < kvend; kv0 += 64) {
        unsigned short* pb = &Pb[w][(kv0 >> 6) & 1][0];

        float4_t st[4];
#pragma unroll
        for (int t = 0; t < 4; t++) {
            short8_t kf = *(const short8_t*)(kbase + (size_t)(kv0 + 16 * t + l16) * D_ + quad * 8);
            st[t] = __builtin_amdgcn_mfma_f32_16x16x32_bf16(kf, qf, zc, 0, 0, 0);
        }

        float psum = 0.f;
#pragma unroll
        for (int t = 0; t < 4; t++) {
            float p0 = exp2f(st[t][0]);
            float p1 = exp2f(st[t][1]);
            float p2 = exp2f(st[t][2]);
            float p3 = exp2f(st[t][3]);
            psum += (p0 + p1) + (p2 + p3);
            unsigned int u0 = pack2tr(p0, p1);
            unsigned int u1 = pack2tr(p2, p3);
            int phys = (2 * t + (quad >> 1)) ^ h7;
            *(uint2*)(pb + l16 * 64 + phys * 8 + (quad & 1) * 4) = make_uint2(u0, u1);
        }
        l_lane += psum;

        short8_t pfa = *(const short8_t*)(pb + l16 * 64 + (quad ^ h7) * 8);
        short8_t pfb = *(const short8_t*)(pb + l16 * 64 + ((4 + quad) ^ h7) * 8);

        short8_t vf00 = *(const short8_t*)(vbase + (size_t)l16 * M_ + kv0 + quad * 8);
        short8_t vf01 = *(const short8_t*)(vbase + (size_t)l16 * M_ + kv0 + 32 + quad * 8);
        short8_t vf10 = *(const short8_t*)(vbase + (size_t)(16 + l16) * M_ + kv0 + quad * 8);
        short8_t vf11 = *(const short8_t*)(vbase + (size_t)(16 + l16) * M_ + kv0 + 32 + quad * 8);
        od0 = __builtin_amdgcn_mfma_f32_16x16x32_bf16(vf00, pfa, od0, 0, 0, 0);
        od0 = __builtin_amdgcn_mfma_f32_16x16x32_bf16(vf01, pfb, od0, 0, 0, 0);
        od1 = __builtin_amdgcn_mfma_f32_16x16x32_bf16(vf10, pfa, od1, 0, 0, 0);
        od1 = __builtin_amdgcn_mfma_f32_16x16x32_bf16(vf11, pfb, od1, 0, 0, 0);
    }

    // reduce l across quads (same q-row lives in lanes ^16, ^32)
    l_lane += __shfl_xor(l_lane, 16);
    l_lane += __shfl_xor(l_lane, 32);

    __syncthreads();
    if (half == 1) {
        float* pw = (float*)&Pb[w][0][0];
        *(float4_t*)(pw + lane * 8) = od0;
        *(float4_t*)(pw + lane * 8 + 4) = od1;
        pw[512 + lane] = l_lane;
    }
    __syncthreads();
    if (half == 0) {
        const float* pp = (const float*)&Pb[w + 4][0][0];
        float4_t e0 = *(const float4_t*)(pp + lane * 8);
        float4_t e1 = *(const float4_t*)(pp + lane * 8 + 4);
#pragma unroll
        for (int r = 0; r < 4; r++) { od0[r] += e0[r]; od1[r] += e1[r]; }
        l_lane += pp[512 + lane];

        const float inv = 1.0f / l_lane;
        unsigned short* ob = att_g + (size_t)(b * N_ + n0 + l16) * D_ + h * DH_;
        unsigned int u0 = pack2rn(od0[0] * inv, od0[1] * inv);
        unsigned int u1 = pack2rn(od0[2] * inv, od0[3] * inv);
        *(uint2*)(ob + quad * 4) = make_uint2(u0, u1);
        unsigned int u2 = pack2rn(od1[0] * inv, od1[1] * inv);
        unsigned int u3 = pack2rn(od1[2] * inv, od1[3] * inv);
        *(uint2*)(ob + 16 + quad * 4) = make_uint2(u2, u3);
    }
}

// ---------------------------------------------------------------------------
// MFMA GEMM: out = concat(pf, att) @ Wf.T + bf, fp32 out. 64x32 tiles,
// 32KB LDS -> 4+ blocks/CU. grid = (ROWS/64)*8 = 1024.
// ---------------------------------------------------------------------------
__global__ __launch_bounds__(256) void g_fuse(
    const unsigned short* __restrict__ pf_g,
    const unsigned short* __restrict__ att_g,
    const float* __restrict__ Wf, const float* __restrict__ bfb,
    float* __restrict__ out)
{
    const int tid = threadIdx.x;
    const int wave = tid >> 6, lane = tid & 63, quad = lane >> 4, l16 = lane & 15;
    const int row0 = ((int)blockIdx.x >> 3) * 64;
    const int col0 = ((int)blockIdx.x & 7) * 32;

    __shared__ unsigned short Bs[32 * 512];  // 32 KB

    stageB<512, 32>(Wf, col0, Bs, tid);
    __syncthreads();

    float4_t acc[2];
#pragma unroll
    for (int c = 0; c < 2; c++) acc[c] = (float4_t){0.f, 0.f, 0.f, 0.f};

    const size_t arow = (size_t)(row0 + wave * 16 + l16) * D_;
#pragma unroll
    for (int k0 = 0; k0 < 512; k0 += 32) {
        const unsigned short* xsrc = (k0 < 256) ? (pf_g + arow + k0) : (att_g + arow + (k0 - 256));
        short8_t af = *(const short8_t*)(xsrc + quad * 8);
#pragma unroll
        for (int c = 0; c < 2; c++)
            acc[c] = __builtin_amdgcn_mfma_f32_16x16x32_bf16(af, readB<512>(Bs, c, l16, quad, k0), acc[c], 0, 0, 0);
    }
#pragma unroll
    for (int c = 0; c < 2; c++) {
        int col = col0 + 16 * c + l16;
        float bb = bfb[col];
#pragma unroll
        for (int r = 0; r < 4; r++) {
            int row = row0 + wave * 16 + quad * 4 + r;
            out[(size_t)row * D_ + col] = acc[c][r] + bb;
        }
    }
}

// ---------------------------------------------------------------------------
extern "C" void kernel_launch(void* const* d_in, const int* in_sizes, int n_in,
                              void* d_out, int out_size, void* d_ws, size_t ws_size,
                              hipStream_t stream)
{
    const float* points = (const float*)d_in[0];
    const float* voxel  = (const float*)d_in[1];
    const float* Wp  = (const float*)d_in[2];
    const float* bp  = (const float*)d_in[3];
    const float* Wq  = (const float*)d_in[4];
    const float* bq  = (const float*)d_in[5];
    const float* Wk  = (const float*)d_in[6];
    const float* bk  = (const float*)d_in[7];
    const float* Wv  = (const float*)d_in[8];
    const float* bv  = (const float*)d_in[9];
    const float* Wf  = (const float*)d_in[10];
    const float* bfb = (const float*)d_in[11];
    float* out = (float*)d_out;

    unsigned short* ws = (unsigned short*)d_ws;
    unsigned short* pf_g  = ws;                               // 8192*256 bf16
    unsigned short* q_g   = pf_g  + (size_t)ROWS_ * D_;       // pre-scaled by PRE_
    unsigned short* k_g   = q_g   + (size_t)ROWS_ * D_;
    unsigned short* vt_g  = k_g   + (size_t)KVROWS_ * D_;     // [b][h][dh][m]
    unsigned short* att_g = vt_g  + (size_t)KVROWS_ * D_;

    n_pf   <<<dim3(ROWS_), dim3(256), 0, stream>>>(points, Wp, bp, pf_g);
    g_qkv  <<<dim3(768),   dim3(256), 0, stream>>>(pf_g, voxel, Wq, bq, Wk, bk, Wv, bv,
                                                   q_g, k_g, vt_g);
    k_attn4<<<dim3(B_ * H_ * (N_ / 64)), dim3(512), 0, stream>>>(q_g, k_g, vt_g, att_g);
    g_fuse <<<dim3((ROWS_ / 64) * 8), dim3(256), 0, stream>>>(pf_g, att_g, Wf, bfb, out);
}

// Round 12
// 169.197 us; speedup vs baseline: 1.3868x; 1.3868x over previous
//
#include <hip/hip_runtime.h>

#define B_ 2
#define N_ 4096
#define M_ 2048
#define D_ 256
#define H_ 8
#define DH_ 32
#define ROWS_ (B_*N_)
#define KVROWS_ (B_*M_)
// SCALE * log2(e): q pre-scaled so softmax = exp2
#define PRE_ (0.17677669529663687f * 1.4426950408889634f)
#define CBASE_ 32.0f

typedef __attribute__((ext_vector_type(8))) short short8_t;
typedef __attribute__((ext_vector_type(4))) float float4_t;

__device__ __forceinline__ unsigned short f2us(float f) {
    union { float f; unsigned int u; } c;
    c.f = f;
    unsigned int u = c.u;
    unsigned int r = u + 0x7FFFu + ((u >> 16) & 1u);  // RTNE
    return (unsigned short)(r >> 16);
}

__device__ __forceinline__ unsigned int pack2rn(float a, float b) {
    return (unsigned int)f2us(a) | ((unsigned int)f2us(b) << 16);
}

// truncation pack (P tiles only; <=2^-8 rel err)
__device__ __forceinline__ unsigned int pack2tr(float a, float b) {
    union { float f; unsigned int u; } x, y;
    x.f = a; y.f = b;
    return (x.u >> 16) | (y.u & 0xFFFF0000u);
}

__device__ __forceinline__ short8_t cvt8(float4 a, float4 b) {
    union { unsigned int u[4]; short8_t s; } c;
    c.u[0] = pack2rn(a.x, a.y);
    c.u[1] = pack2rn(a.z, a.w);
    c.u[2] = pack2rn(b.x, b.y);
    c.u[3] = pack2rn(b.z, b.w);
    return c.s;
}

// ---------------------------------------------------------------------------
// pf[row,o] = points[row,:] @ Wp[o,:] + bp[o]
// ---------------------------------------------------------------------------
__global__ __launch_bounds__(256) void n_pf(
    const float* __restrict__ points, const float* __restrict__ Wp,
    const float* __restrict__ bp, unsigned short* __restrict__ pf_g)
{
    const int row = blockIdx.x;
    const int o = threadIdx.x;
    const float p0 = points[(size_t)row * 3 + 0];
    const float p1 = points[(size_t)row * 3 + 1];
    const float p2 = points[(size_t)row * 3 + 2];
    float v = p0 * Wp[o * 3 + 0] + p1 * Wp[o * 3 + 1] + p2 * Wp[o * 3 + 2] + bp[o];
    pf_g[(size_t)row * D_ + o] = f2us(v);
}

// ---------------------------------------------------------------------------
// Stage NCOL x K fp32 weight block into XOR-swizzled bf16 LDS.
// ---------------------------------------------------------------------------
template<int K, int NCOL>
__device__ __forceinline__ void stageB(const float* __restrict__ W, int col0,
                                       unsigned short* __restrict__ Bs, int tid)
{
    const int n = tid & (NCOL - 1), g = tid / NCOL;
    const int GROUPS = 256 / NCOL;
    const int CPT = (K / 8) / GROUPS;
    const float* src = W + (size_t)(col0 + n) * K + g * (K / GROUPS);
#pragma unroll
    for (int ci = 0; ci < CPT; ci++) {
        int logc = g * CPT + ci;
        int phys = logc ^ (n & 7);
        short8_t v = cvt8(*(const float4*)(src + ci * 8), *(const float4*)(src + ci * 8 + 4));
        *(short8_t*)(Bs + (size_t)n * K + phys * 8) = v;
    }
}

template<int K>
__device__ __forceinline__ short8_t readB(const unsigned short* __restrict__ Bs,
                                          int c, int l16, int quad, int k0)
{
    int phys = ((k0 >> 3) + quad) ^ (l16 & 7);
    return *(const short8_t*)(Bs + (size_t)(16 * c + l16) * K + phys * 8);
}

// ---------------------------------------------------------------------------
// Merged projection kernel (unchanged; passed rounds 10-11 logic-wise).
// ---------------------------------------------------------------------------
__global__ __launch_bounds__(256) void g_qkv(
    const unsigned short* __restrict__ pf_g, const float* __restrict__ voxel,
    const float* __restrict__ Wq, const float* __restrict__ bq,
    const float* __restrict__ Wk, const float* __restrict__ bk,
    const float* __restrict__ Wv, const float* __restrict__ bv,
    unsigned short* __restrict__ q_g, unsigned short* __restrict__ k_g,
    unsigned short* __restrict__ vt_g)
{
    const int tid = threadIdx.x;
    const int wave = tid >> 6, lane = tid & 63, quad = lane >> 4, l16 = lane & 15;

    __shared__ unsigned short Bs[64 * 256];  // 32 KB

    if (blockIdx.x < 512) {
        const int row0 = ((int)blockIdx.x >> 2) * 64;
        const int col0 = ((int)blockIdx.x & 3) * 64;
        stageB<256, 64>(Wq, col0, Bs, tid);
        __syncthreads();
        float4_t acc[4];
#pragma unroll
        for (int c = 0; c < 4; c++) acc[c] = (float4_t){0.f, 0.f, 0.f, 0.f};
        const unsigned short* arow = pf_g + (size_t)(row0 + wave * 16 + l16) * D_;
#pragma unroll
        for (int k0 = 0; k0 < 256; k0 += 32) {
            short8_t af = *(const short8_t*)(arow + k0 + quad * 8);
#pragma unroll
            for (int c = 0; c < 4; c++)
                acc[c] = __builtin_amdgcn_mfma_f32_16x16x32_bf16(af, readB<256>(Bs, c, l16, quad, k0), acc[c], 0, 0, 0);
        }
#pragma unroll
        for (int c = 0; c < 4; c++) {
            int col = col0 + 16 * c + l16;
            float bb = bq[col];
#pragma unroll
            for (int r = 0; r < 4; r++) {
                int row = row0 + wave * 16 + quad * 4 + r;
                q_g[(size_t)row * D_ + col] = f2us((acc[c][r] + bb) * PRE_);
            }
        }
    } else {
        const int bid = (int)blockIdx.x - 512;
        const int row0 = (bid >> 2) * 64;
        const int col0 = (bid & 3) * 64;
        const float* arow = voxel + (size_t)(row0 + wave * 16 + l16) * D_;

        float4_t ak[4], av[4];
#pragma unroll
        for (int c = 0; c < 4; c++) {
            ak[c] = (float4_t){0.f, 0.f, 0.f, 0.f};
            av[c] = (float4_t){0.f, 0.f, 0.f, 0.f};
        }
        stageB<256, 64>(Wk, col0, Bs, tid);
        __syncthreads();
#pragma unroll
        for (int k0 = 0; k0 < 256; k0 += 32) {
            short8_t af = cvt8(*(const float4*)(arow + k0 + quad * 8),
                               *(const float4*)(arow + k0 + quad * 8 + 4));
#pragma unroll
            for (int c = 0; c < 4; c++)
                ak[c] = __builtin_amdgcn_mfma_f32_16x16x32_bf16(af, readB<256>(Bs, c, l16, quad, k0), ak[c], 0, 0, 0);
        }
        __syncthreads();
        stageB<256, 64>(Wv, col0, Bs, tid);
        __syncthreads();
#pragma unroll
        for (int k0 = 0; k0 < 256; k0 += 32) {
            short8_t af = cvt8(*(const float4*)(arow + k0 + quad * 8),
                               *(const float4*)(arow + k0 + quad * 8 + 4));
#pragma unroll
            for (int c = 0; c < 4; c++)
                av[c] = __builtin_amdgcn_mfma_f32_16x16x32_bf16(af, readB<256>(Bs, c, l16, quad, k0), av[c], 0, 0, 0);
        }
        const int b = row0 / M_;
        const int m0 = row0 - b * M_ + wave * 16 + quad * 4;
#pragma unroll
        for (int c = 0; c < 4; c++) {
            int col = col0 + 16 * c + l16;
            float bbk = bk[col], bbv = bv[col];
#pragma unroll
            for (int r = 0; r < 4; r++) {
                int row = row0 + wave * 16 + quad * 4 + r;
                k_g[(size_t)row * D_ + col] = f2us(ak[c][r] + bbk);
            }
            int h = col >> 5, dh = col & 31;
            unsigned int u0 = pack2rn(av[c][0] + bbv, av[c][1] + bbv);
            unsigned int u1 = pack2rn(av[c][2] + bbv, av[c][3] + bbv);
            *(uint2*)(vt_g + (size_t)((b * H_ + h) * DH_ + dh) * M_ + m0) = make_uint2(u0, u1);
        }
    }
}

// ---------------------------------------------------------------------------
// MFMA flash attention with BLOCK-COOPERATIVE K/V LDS staging.
// grid: B*H*(N/128) = 512 blocks, 512 threads (8 waves; wave w -> 16 q-rows).
// Per 64-kv step: threads<256 stage K tile (64x32, rows padded to 40),
// threads>=256 stage V^T tile (32x64, rows padded to 72) — coalesced, ONCE
// per block (8x fewer L1 line-requests than per-wave gathers). Double
// buffered, one barrier/step. Static-base softmax (validated r9/r11).
// ---------------------------------------------------------------------------
__global__ __launch_bounds__(512) void k_attn5(
    const unsigned short* __restrict__ q_g,
    const unsigned short* __restrict__ k_g,
    const unsigned short* __restrict__ vt_g,
    unsigned short* __restrict__ att_g)
{
    const int tid = threadIdx.x;
    const int w = tid >> 6, lane = tid & 63, quad = lane >> 4, l16 = lane & 15;
    const int nt = blockIdx.x & 31;       // N/128
    const int bh = blockIdx.x >> 5;       // b*8+h
    const int b = bh >> 3, h = bh & 7;
    const int n0 = nt * 128 + w * 16;

    __shared__ unsigned short Kt[2][64][40];   // 10.2 KB
    __shared__ unsigned short Vt[2][32][72];   //  9.2 KB
    __shared__ unsigned short Pb[8][16][64];   // 16   KB

    short8_t qf = *(const short8_t*)(q_g + (size_t)(b * N_ + n0 + l16) * D_ + h * DH_ + quad * 8);

    float4_t od0 = {0.f, 0.f, 0.f, 0.f};
    float4_t od1 = {0.f, 0.f, 0.f, 0.f};
    float l_lane = 0.f;

    const unsigned short* kbase = k_g + (size_t)(b * M_) * D_ + h * DH_;
    const unsigned short* vbase = vt_g + (size_t)(bh * DH_) * M_;
    unsigned short* pb = &Pb[w][0][0];
    const int h7 = l16 & 7;
    const float4_t zc = {-CBASE_, -CBASE_, -CBASE_, -CBASE_};

    // staging roles
    const int kr = tid >> 2, kc = tid & 3;            // tid < 256: K row/chunk
    const int vr = (tid - 256) >> 3, vc = tid & 7;    // tid >= 256: V row/chunk

    // prologue: stage step 0 into buf 0
    if (tid < 256) {
        *(short8_t*)&Kt[0][kr][kc * 8] =
            *(const short8_t*)(kbase + (size_t)kr * D_ + kc * 8);
    } else {
        *(short8_t*)&Vt[0][vr][vc * 8] =
            *(const short8_t*)(vbase + (size_t)vr * M_ + vc * 8);
    }

    for (int s = 0; s < M_ / 64; s++) {
        __syncthreads();
        const int buf = s & 1;
        // prefetch step s+1 into buf^1 (safe: all waves done reading it)
        if (s + 1 < M_ / 64) {
            const int kv1 = (s + 1) * 64;
            if (tid < 256) {
                *(short8_t*)&Kt[buf ^ 1][kr][kc * 8] =
                    *(const short8_t*)(kbase + (size_t)(kv1 + kr) * D_ + kc * 8);
            } else {
                *(short8_t*)&Vt[buf ^ 1][vr][vc * 8] =
                    *(const short8_t*)(vbase + (size_t)vr * M_ + kv1 + vc * 8);
            }
        }

        float4_t st[4];
#pragma unroll
        for (int t = 0; t < 4; t++) {
            short8_t kf = *(const short8_t*)&Kt[buf][16 * t + l16][quad * 8];
            st[t] = __builtin_amdgcn_mfma_f32_16x16x32_bf16(kf, qf, zc, 0, 0, 0);
        }

        float psum = 0.f;
#pragma unroll
        for (int t = 0; t < 4; t++) {
            float p0 = exp2f(st[t][0]);
            float p1 = exp2f(st[t][1]);
            float p2 = exp2f(st[t][2]);
            float p3 = exp2f(st[t][3]);
            psum += (p0 + p1) + (p2 + p3);
            unsigned int u0 = pack2tr(p0, p1);
            unsigned int u1 = pack2tr(p2, p3);
            int phys = (2 * t + (quad >> 1)) ^ h7;
            *(uint2*)(pb + l16 * 64 + phys * 8 + (quad & 1) * 4) = make_uint2(u0, u1);
        }
        l_lane += psum;

        short8_t pfa = *(const short8_t*)(pb + l16 * 64 + (quad ^ h7) * 8);
        short8_t pfb = *(const short8_t*)(pb + l16 * 64 + ((4 + quad) ^ h7) * 8);

        short8_t vf00 = *(const short8_t*)&Vt[buf][l16][quad * 8];
        short8_t vf01 = *(const short8_t*)&Vt[buf][l16][32 + quad * 8];
        short8_t vf10 = *(const short8_t*)&Vt[buf][16 + l16][quad * 8];
        short8_t vf11 = *(const short8_t*)&Vt[buf][16 + l16][32 + quad * 8];
        od0 = __builtin_amdgcn_mfma_f32_16x16x32_bf16(vf00, pfa, od0, 0, 0, 0);
        od0 = __builtin_amdgcn_mfma_f32_16x16x32_bf16(vf01, pfb, od0, 0, 0, 0);
        od1 = __builtin_amdgcn_mfma_f32_16x16x32_bf16(vf10, pfa, od1, 0, 0, 0);
        od1 = __builtin_amdgcn_mfma_f32_16x16x32_bf16(vf11, pfb, od1, 0, 0, 0);
    }

    // reduce l across quads (same q-row lives in lanes ^16, ^32)
    l_lane += __shfl_xor(l_lane, 16);
    l_lane += __shfl_xor(l_lane, 32);
    const float inv = 1.0f / l_lane;

    unsigned short* ob = att_g + (size_t)(b * N_ + n0 + l16) * D_ + h * DH_;
    {
        unsigned int u0 = pack2rn(od0[0] * inv, od0[1] * inv);
        unsigned int u1 = pack2rn(od0[2] * inv, od0[3] * inv);
        *(uint2*)(ob + quad * 4) = make_uint2(u0, u1);
        unsigned int u2 = pack2rn(od1[0] * inv, od1[1] * inv);
        unsigned int u3 = pack2rn(od1[2] * inv, od1[3] * inv);
        *(uint2*)(ob + 16 + quad * 4) = make_uint2(u2, u3);
    }
}

// ---------------------------------------------------------------------------
// MFMA GEMM: out = concat(pf, att) @ Wf.T + bf, fp32 out. 64x32 tiles.
// ---------------------------------------------------------------------------
__global__ __launch_bounds__(256) void g_fuse(
    const unsigned short* __restrict__ pf_g,
    const unsigned short* __restrict__ att_g,
    const float* __restrict__ Wf, const float* __restrict__ bfb,
    float* __restrict__ out)
{
    const int tid = threadIdx.x;
    const int wave = tid >> 6, lane = tid & 63, quad = lane >> 4, l16 = lane & 15;
    const int row0 = ((int)blockIdx.x >> 3) * 64;
    const int col0 = ((int)blockIdx.x & 7) * 32;

    __shared__ unsigned short Bs[32 * 512];  // 32 KB

    stageB<512, 32>(Wf, col0, Bs, tid);
    __syncthreads();

    float4_t acc[2];
#pragma unroll
    for (int c = 0; c < 2; c++) acc[c] = (float4_t){0.f, 0.f, 0.f, 0.f};

    const size_t arow = (size_t)(row0 + wave * 16 + l16) * D_;
#pragma unroll
    for (int k0 = 0; k0 < 512; k0 += 32) {
        const unsigned short* xsrc = (k0 < 256) ? (pf_g + arow + k0) : (att_g + arow + (k0 - 256));
        short8_t af = *(const short8_t*)(xsrc + quad * 8);
#pragma unroll
        for (int c = 0; c < 2; c++)
            acc[c] = __builtin_amdgcn_mfma_f32_16x16x32_bf16(af, readB<512>(Bs, c, l16, quad, k0), acc[c], 0, 0, 0);
    }
#pragma unroll
    for (int c = 0; c < 2; c++) {
        int col = col0 + 16 * c + l16;
        float bb = bfb[col];
#pragma unroll
        for (int r = 0; r < 4; r++) {
            int row = row0 + wave * 16 + quad * 4 + r;
            out[(size_t)row * D_ + col] = acc[c][r] + bb;
        }
    }
}

// ---------------------------------------------------------------------------
extern "C" void kernel_launch(void* const* d_in, const int* in_sizes, int n_in,
                              void* d_out, int out_size, void* d_ws, size_t ws_size,
                              hipStream_t stream)
{
    const float* points = (const float*)d_in[0];
    const float* voxel  = (const float*)d_in[1];
    const float* Wp  = (const float*)d_in[2];
    const float* bp  = (const float*)d_in[3];
    const float* Wq  = (const float*)d_in[4];
    const float* bq  = (const float*)d_in[5];
    const float* Wk  = (const float*)d_in[6];
    const float* bk  = (const float*)d_in[7];
    const float* Wv  = (const float*)d_in[8];
    const float* bv  = (const float*)d_in[9];
    const float* Wf  = (const float*)d_in[10];
    const float* bfb = (const float*)d_in[11];
    float* out = (float*)d_out;

    unsigned short* ws = (unsigned short*)d_ws;
    unsigned short* pf_g  = ws;                               // 8192*256 bf16
    unsigned short* q_g   = pf_g  + (size_t)ROWS_ * D_;       // pre-scaled by PRE_
    unsigned short* k_g   = q_g   + (size_t)ROWS_ * D_;
    unsigned short* vt_g  = k_g   + (size_t)KVROWS_ * D_;     // [b][h][dh][m]
    unsigned short* att_g = vt_g  + (size_t)KVROWS_ * D_;

    n_pf   <<<dim3(ROWS_), dim3(256), 0, stream>>>(points, Wp, bp, pf_g);
    g_qkv  <<<dim3(768),   dim3(256), 0, stream>>>(pf_g, voxel, Wq, bq, Wk, bk, Wv, bv,
                                                   q_g, k_g, vt_g);
    k_attn5<<<dim3(B_ * H_ * (N_ / 128)), dim3(512), 0, stream>>>(q_g, k_g, vt_g, att_g);
    g_fuse <<<dim3((ROWS_ / 64) * 8), dim3(256), 0, stream>>>(pf_g, att_g, Wf, bfb, out);
}

// Round 13
// 157.011 us; speedup vs baseline: 1.4944x; 1.0776x over previous
//
#include <hip/hip_runtime.h>

#define B_ 2
#define N_ 4096
#define M_ 2048
#define D_ 256
#define H_ 8
#define DH_ 32
#define ROWS_ (B_*N_)
#define KVROWS_ (B_*M_)
// SCALE * log2(e): q pre-scaled so softmax = exp2
#define PRE_ (0.17677669529663687f * 1.4426950408889634f)
#define CBASE_ 32.0f

typedef __attribute__((ext_vector_type(8))) short short8_t;
typedef __attribute__((ext_vector_type(4))) float float4_t;

// native exp2 if the compiler-known builtin exists (hazard-safe, unlike raw asm)
#if defined(__has_builtin)
# if __has_builtin(__builtin_amdgcn_exp2f)
#  define EXP2F(x) __builtin_amdgcn_exp2f(x)
# else
#  define EXP2F(x) exp2f(x)
# endif
#else
# define EXP2F(x) exp2f(x)
#endif

__device__ __forceinline__ unsigned short f2us(float f) {
    union { float f; unsigned int u; } c;
    c.f = f;
    unsigned int u = c.u;
    unsigned int r = u + 0x7FFFu + ((u >> 16) & 1u);  // RTNE
    return (unsigned short)(r >> 16);
}

__device__ __forceinline__ unsigned int pack2rn(float a, float b) {
    return (unsigned int)f2us(a) | ((unsigned int)f2us(b) << 16);
}

// truncation pack (P tiles only; <=2^-8 rel err)
__device__ __forceinline__ unsigned int pack2tr(float a, float b) {
    union { float f; unsigned int u; } x, y;
    x.f = a; y.f = b;
    return (x.u >> 16) | (y.u & 0xFFFF0000u);
}

__device__ __forceinline__ short8_t cvt8(float4 a, float4 b) {
    union { unsigned int u[4]; short8_t s; } c;
    c.u[0] = pack2rn(a.x, a.y);
    c.u[1] = pack2rn(a.z, a.w);
    c.u[2] = pack2rn(b.x, b.y);
    c.u[3] = pack2rn(b.z, b.w);
    return c.s;
}

// ---------------------------------------------------------------------------
// Stage NCOL x K fp32 weight block into XOR-swizzled bf16 LDS.
// ---------------------------------------------------------------------------
template<int K, int NCOL>
__device__ __forceinline__ void stageB(const float* __restrict__ W, int col0,
                                       unsigned short* __restrict__ Bs, int tid)
{
    const int n = tid & (NCOL - 1), g = tid / NCOL;
    const int GROUPS = 256 / NCOL;
    const int CPT = (K / 8) / GROUPS;
    const float* src = W + (size_t)(col0 + n) * K + g * (K / GROUPS);
#pragma unroll
    for (int ci = 0; ci < CPT; ci++) {
        int logc = g * CPT + ci;
        int phys = logc ^ (n & 7);
        short8_t v = cvt8(*(const float4*)(src + ci * 8), *(const float4*)(src + ci * 8 + 4));
        *(short8_t*)(Bs + (size_t)n * K + phys * 8) = v;
    }
}

template<int K>
__device__ __forceinline__ short8_t readB(const unsigned short* __restrict__ Bs,
                                          int c, int l16, int quad, int k0)
{
    int phys = ((k0 >> 3) + quad) ^ (l16 & 7);
    return *(const short8_t*)(Bs + (size_t)(16 * c + l16) * K + phys * 8);
}

// ---------------------------------------------------------------------------
// Merged projection kernel.
// blocks [0,512): q-role — pf computed INLINE from Wp (LDS, stride-5 padded,
//   quad-broadcast reads), pf stored by col0==0 blocks, q = pf@Wq.T (PRE_).
// blocks [512,768): kv-role — k = voxel@Wk.T -> k_g; v = voxel@Wv.T -> vt_g
//   (transposed), two passes over one 32KB B-stage.
// ---------------------------------------------------------------------------
__global__ __launch_bounds__(256) void g_proj(
    const float* __restrict__ points, const float* __restrict__ voxel,
    const float* __restrict__ Wp, const float* __restrict__ bp,
    const float* __restrict__ Wq, const float* __restrict__ bq,
    const float* __restrict__ Wk, const float* __restrict__ bk,
    const float* __restrict__ Wv, const float* __restrict__ bv,
    unsigned short* __restrict__ pf_g, unsigned short* __restrict__ q_g,
    unsigned short* __restrict__ k_g, unsigned short* __restrict__ vt_g)
{
    const int tid = threadIdx.x;
    const int wave = tid >> 6, lane = tid & 63, quad = lane >> 4, l16 = lane & 15;

    __shared__ unsigned short Bs[64 * 256];  // 32 KB
    __shared__ float Wp_lds[256 * 5];        //  5 KB (stride 5: bank-clean)

    if (blockIdx.x < 512) {
        const int row0 = ((int)blockIdx.x >> 2) * 64;
        const int col0 = ((int)blockIdx.x & 3) * 64;
        stageB<256, 64>(Wq, col0, Bs, tid);
        Wp_lds[tid * 5 + 0] = Wp[tid * 3 + 0];
        Wp_lds[tid * 5 + 1] = Wp[tid * 3 + 1];
        Wp_lds[tid * 5 + 2] = Wp[tid * 3 + 2];
        Wp_lds[tid * 5 + 3] = bp[tid];
        __syncthreads();

        const int n = row0 + wave * 16 + l16;
        const float p0 = points[(size_t)n * 3 + 0];
        const float p1 = points[(size_t)n * 3 + 1];
        const float p2 = points[(size_t)n * 3 + 2];

        float4_t acc[4];
#pragma unroll
        for (int c = 0; c < 4; c++) acc[c] = (float4_t){0.f, 0.f, 0.f, 0.f};

#pragma unroll
        for (int k0 = 0; k0 < 256; k0 += 32) {
            float pf[8];
#pragma unroll
            for (int j = 0; j < 8; j++) {
                int c = k0 + quad * 8 + j;
                pf[j] = p0 * Wp_lds[c * 5 + 0] + p1 * Wp_lds[c * 5 + 1]
                      + p2 * Wp_lds[c * 5 + 2] + Wp_lds[c * 5 + 3];
            }
            short8_t af = cvt8(make_float4(pf[0], pf[1], pf[2], pf[3]),
                               make_float4(pf[4], pf[5], pf[6], pf[7]));
            if (col0 == 0)
                *(short8_t*)(pf_g + (size_t)n * D_ + k0 + quad * 8) = af;
#pragma unroll
            for (int c = 0; c < 4; c++)
                acc[c] = __builtin_amdgcn_mfma_f32_16x16x32_bf16(af, readB<256>(Bs, c, l16, quad, k0), acc[c], 0, 0, 0);
        }
#pragma unroll
        for (int c = 0; c < 4; c++) {
            int col = col0 + 16 * c + l16;
            float bb = bq[col];
#pragma unroll
            for (int r = 0; r < 4; r++) {
                int row = row0 + wave * 16 + quad * 4 + r;
                q_g[(size_t)row * D_ + col] = f2us((acc[c][r] + bb) * PRE_);
            }
        }
    } else {
        const int bid = (int)blockIdx.x - 512;
        const int row0 = (bid >> 2) * 64;
        const int col0 = (bid & 3) * 64;
        const float* arow = voxel + (size_t)(row0 + wave * 16 + l16) * D_;

        float4_t ak[4], av[4];
#pragma unroll
        for (int c = 0; c < 4; c++) {
            ak[c] = (float4_t){0.f, 0.f, 0.f, 0.f};
            av[c] = (float4_t){0.f, 0.f, 0.f, 0.f};
        }
        stageB<256, 64>(Wk, col0, Bs, tid);
        __syncthreads();
#pragma unroll
        for (int k0 = 0; k0 < 256; k0 += 32) {
            short8_t af = cvt8(*(const float4*)(arow + k0 + quad * 8),
                               *(const float4*)(arow + k0 + quad * 8 + 4));
#pragma unroll
            for (int c = 0; c < 4; c++)
                ak[c] = __builtin_amdgcn_mfma_f32_16x16x32_bf16(af, readB<256>(Bs, c, l16, quad, k0), ak[c], 0, 0, 0);
        }
        __syncthreads();
        stageB<256, 64>(Wv, col0, Bs, tid);
        __syncthreads();
#pragma unroll
        for (int k0 = 0; k0 < 256; k0 += 32) {
            short8_t af = cvt8(*(const float4*)(arow + k0 + quad * 8),
                               *(const float4*)(arow + k0 + quad * 8 + 4));
#pragma unroll
            for (int c = 0; c < 4; c++)
                av[c] = __builtin_amdgcn_mfma_f32_16x16x32_bf16(af, readB<256>(Bs, c, l16, quad, k0), av[c], 0, 0, 0);
        }
        const int b = row0 / M_;
        const int m0 = row0 - b * M_ + wave * 16 + quad * 4;
#pragma unroll
        for (int c = 0; c < 4; c++) {
            int col = col0 + 16 * c + l16;
            float bbk = bk[col], bbv = bv[col];
#pragma unroll
            for (int r = 0; r < 4; r++) {
                int row = row0 + wave * 16 + quad * 4 + r;
                k_g[(size_t)row * D_ + col] = f2us(ak[c][r] + bbk);
            }
            int h = col >> 5, dh = col & 31;
            unsigned int u0 = pack2rn(av[c][0] + bbv, av[c][1] + bbv);
            unsigned int u1 = pack2rn(av[c][2] + bbv, av[c][3] + bbv);
            *(uint2*)(vt_g + (size_t)((b * H_ + h) * DH_ + dh) * M_ + m0) = make_uint2(u0, u1);
        }
    }
}

// ---------------------------------------------------------------------------
// MFMA flash attention, cooperative dbuf staging, 64 q-rows/block.
// grid: B*H*(N/64) = 1024 blocks, 256 threads (4 waves) -> 4 blocks/CU.
// Each thread stages one K chunk AND one V chunk per step.
// ---------------------------------------------------------------------------
__global__ __launch_bounds__(256) void k_attn6(
    const unsigned short* __restrict__ q_g,
    const unsigned short* __restrict__ k_g,
    const unsigned short* __restrict__ vt_g,
    unsigned short* __restrict__ att_g)
{
    const int tid = threadIdx.x;
    const int w = tid >> 6, lane = tid & 63, quad = lane >> 4, l16 = lane & 15;
    const int nt = blockIdx.x & 63;       // N/64
    const int bh = blockIdx.x >> 6;       // b*8+h
    const int b = bh >> 3, h = bh & 7;
    const int n0 = nt * 64 + w * 16;

    __shared__ unsigned short Kt[2][64][40];   // 10.2 KB
    __shared__ unsigned short Vt[2][32][72];   //  9.2 KB
    __shared__ unsigned short Pb[4][16][64];   //  8   KB

    short8_t qf = *(const short8_t*)(q_g + (size_t)(b * N_ + n0 + l16) * D_ + h * DH_ + quad * 8);

    float4_t od0 = {0.f, 0.f, 0.f, 0.f};
    float4_t od1 = {0.f, 0.f, 0.f, 0.f};
    float l_lane = 0.f;

    const unsigned short* kbase = k_g + (size_t)(b * M_) * D_ + h * DH_;
    const unsigned short* vbase = vt_g + (size_t)(bh * DH_) * M_;
    unsigned short* pb = &Pb[w][0][0];
    const int h7 = l16 & 7;
    const float4_t zc = {-CBASE_, -CBASE_, -CBASE_, -CBASE_};

    // staging roles: each thread does one K chunk + one V chunk
    const int kr = tid >> 2, kc = tid & 3;   // K: 64 rows x 4 chunks
    const int vr = tid >> 3, vc = tid & 7;   // V: 32 rows x 8 chunks

    // prologue: stage step 0 into buf 0
    *(short8_t*)&Kt[0][kr][kc * 8] = *(const short8_t*)(kbase + (size_t)kr * D_ + kc * 8);
    *(short8_t*)&Vt[0][vr][vc * 8] = *(const short8_t*)(vbase + (size_t)vr * M_ + vc * 8);

    for (int s = 0; s < M_ / 64; s++) {
        __syncthreads();
        const int buf = s & 1;
        if (s + 1 < M_ / 64) {
            const int kv1 = (s + 1) * 64;
            *(short8_t*)&Kt[buf ^ 1][kr][kc * 8] =
                *(const short8_t*)(kbase + (size_t)(kv1 + kr) * D_ + kc * 8);
            *(short8_t*)&Vt[buf ^ 1][vr][vc * 8] =
                *(const short8_t*)(vbase + (size_t)vr * M_ + kv1 + vc * 8);
        }

        float4_t st[4];
#pragma unroll
        for (int t = 0; t < 4; t++) {
            short8_t kf = *(const short8_t*)&Kt[buf][16 * t + l16][quad * 8];
            st[t] = __builtin_amdgcn_mfma_f32_16x16x32_bf16(kf, qf, zc, 0, 0, 0);
        }

        float psum = 0.f;
#pragma unroll
        for (int t = 0; t < 4; t++) {
            float p0 = EXP2F(st[t][0]);
            float p1 = EXP2F(st[t][1]);
            float p2 = EXP2F(st[t][2]);
            float p3 = EXP2F(st[t][3]);
            psum += (p0 + p1) + (p2 + p3);
            unsigned int u0 = pack2tr(p0, p1);
            unsigned int u1 = pack2tr(p2, p3);
            int phys = (2 * t + (quad >> 1)) ^ h7;
            *(uint2*)(pb + l16 * 64 + phys * 8 + (quad & 1) * 4) = make_uint2(u0, u1);
        }
        l_lane += psum;

        short8_t pfa = *(const short8_t*)(pb + l16 * 64 + (quad ^ h7) * 8);
        short8_t pfb = *(const short8_t*)(pb + l16 * 64 + ((4 + quad) ^ h7) * 8);

        short8_t vf00 = *(const short8_t*)&Vt[buf][l16][quad * 8];
        short8_t vf01 = *(const short8_t*)&Vt[buf][l16][32 + quad * 8];
        short8_t vf10 = *(const short8_t*)&Vt[buf][16 + l16][quad * 8];
        short8_t vf11 = *(const short8_t*)&Vt[buf][16 + l16][32 + quad * 8];
        od0 = __builtin_amdgcn_mfma_f32_16x16x32_bf16(vf00, pfa, od0, 0, 0, 0);
        od0 = __builtin_amdgcn_mfma_f32_16x16x32_bf16(vf01, pfb, od0, 0, 0, 0);
        od1 = __builtin_amdgcn_mfma_f32_16x16x32_bf16(vf10, pfa, od1, 0, 0, 0);
        od1 = __builtin_amdgcn_mfma_f32_16x16x32_bf16(vf11, pfb, od1, 0, 0, 0);
    }

    l_lane += __shfl_xor(l_lane, 16);
    l_lane += __shfl_xor(l_lane, 32);
    const float inv = 1.0f / l_lane;

    unsigned short* ob = att_g + (size_t)(b * N_ + n0 + l16) * D_ + h * DH_;
    {
        unsigned int u0 = pack2rn(od0[0] * inv, od0[1] * inv);
        unsigned int u1 = pack2rn(od0[2] * inv, od0[3] * inv);
        *(uint2*)(ob + quad * 4) = make_uint2(u0, u1);
        unsigned int u2 = pack2rn(od1[0] * inv, od1[1] * inv);
        unsigned int u3 = pack2rn(od1[2] * inv, od1[3] * inv);
        *(uint2*)(ob + 16 + quad * 4) = make_uint2(u2, u3);
    }
}

// ---------------------------------------------------------------------------
// MFMA GEMM: out = concat(pf, att) @ Wf.T + bf, fp32 out. 64x32 tiles.
// ---------------------------------------------------------------------------
__global__ __launch_bounds__(256) void g_fuse(
    const unsigned short* __restrict__ pf_g,
    const unsigned short* __restrict__ att_g,
    const float* __restrict__ Wf, const float* __restrict__ bfb,
    float* __restrict__ out)
{
    const int tid = threadIdx.x;
    const int wave = tid >> 6, lane = tid & 63, quad = lane >> 4, l16 = lane & 15;
    const int row0 = ((int)blockIdx.x >> 3) * 64;
    const int col0 = ((int)blockIdx.x & 7) * 32;

    __shared__ unsigned short Bs[32 * 512];  // 32 KB

    stageB<512, 32>(Wf, col0, Bs, tid);
    __syncthreads();

    float4_t acc[2];
#pragma unroll
    for (int c = 0; c < 2; c++) acc[c] = (float4_t){0.f, 0.f, 0.f, 0.f};

    const size_t arow = (size_t)(row0 + wave * 16 + l16) * D_;
#pragma unroll
    for (int k0 = 0; k0 < 512; k0 += 32) {
        const unsigned short* xsrc = (k0 < 256) ? (pf_g + arow + k0) : (att_g + arow + (k0 - 256));
        short8_t af = *(const short8_t*)(xsrc + quad * 8);
#pragma unroll
        for (int c = 0; c < 2; c++)
            acc[c] = __builtin_amdgcn_mfma_f32_16x16x32_bf16(af, readB<512>(Bs, c, l16, quad, k0), acc[c], 0, 0, 0);
    }
#pragma unroll
    for (int c = 0; c < 2; c++) {
        int col = col0 + 16 * c + l16;
        float bb = bfb[col];
#pragma unroll
        for (int r = 0; r < 4; r++) {
            int row = row0 + wave * 16 + quad * 4 + r;
            out[(size_t)row * D_ + col] = acc[c][r] + bb;
        }
    }
}

// ---------------------------------------------------------------------------
extern "C" void kernel_launch(void* const* d_in, const int* in_sizes, int n_in,
                              void* d_out, int out_size, void* d_ws, size_t ws_size,
                              hipStream_t stream)
{
    const float* points = (const float*)d_in[0];
    const float* voxel  = (const float*)d_in[1];
    const float* Wp  = (const float*)d_in[2];
    const float* bp  = (const float*)d_in[3];
    const float* Wq  = (const float*)d_in[4];
    const float* bq  = (const float*)d_in[5];
    const float* Wk  = (const float*)d_in[6];
    const float* bk  = (const float*)d_in[7];
    const float* Wv  = (const float*)d_in[8];
    const float* bv  = (const float*)d_in[9];
    const float* Wf  = (const float*)d_in[10];
    const float* bfb = (const float*)d_in[11];
    float* out = (float*)d_out;

    unsigned short* ws = (unsigned short*)d_ws;
    unsigned short* pf_g  = ws;                               // 8192*256 bf16
    unsigned short* q_g   = pf_g  + (size_t)ROWS_ * D_;       // pre-scaled by PRE_
    unsigned short* k_g   = q_g   + (size_t)ROWS_ * D_;
    unsigned short* vt_g  = k_g   + (size_t)KVROWS_ * D_;     // [b][h][dh][m]
    unsigned short* att_g = vt_g  + (size_t)KVROWS_ * D_;

    g_proj <<<dim3(768),  dim3(256), 0, stream>>>(points, voxel, Wp, bp, Wq, bq,
                                                  Wk, bk, Wv, bv, pf_g, q_g, k_g, vt_g);
    k_attn6<<<dim3(B_ * H_ * (N_ / 64)), dim3(256), 0, stream>>>(q_g, k_g, vt_g, att_g);
    g_fuse <<<dim3((ROWS_ / 64) * 8), dim3(256), 0, stream>>>(pf_g, att_g, Wf, bfb, out);
}